// Round 1
// baseline (246.264 us; speedup 1.0000x reference)
//
#include <hip/hip_runtime.h>
#include <hip/hip_bf16.h>
#include <stdint.h>

// Shapes: N=32, CIN=COUT=64, T=256, V=25, K3=3, G=8
// GCN folded to one GEMM: M=1600 (m=w*64+c), K=1600 (k=cin*25+v), N=8192 (n,t)
//   residual (+x) folded into U's diagonal: U[w*64+c][c*25+w] += 1
// k_gemm: 256x256 tile, 8 waves, 8-phase counted-vmcnt schedule (T2+T3+T4+T5)
// k_tcn: MFMA im2col, 512-thread blocks (16 waves/CU), DMA staging
//   OOB window rows read from U's pad rows (zeroed by k_pre2 every call)

typedef const float* fp;
typedef __attribute__((ext_vector_type(8))) short short8;   // 8 bf16 (4 VGPRs)
typedef __attribute__((ext_vector_type(4))) float floatx4;  // MFMA acc

__device__ __forceinline__ float us2f(unsigned int u){
  union { unsigned int i; float f; } c; c.i = u << 16; return c.f;
}
__device__ __forceinline__ unsigned short f2us(float f){
  __hip_bfloat16 h = __float2bfloat16(f);
  return *reinterpret_cast<unsigned short*>(&h);
}
__device__ __forceinline__ void gload_lds16(const void* g, void* l){
  __builtin_amdgcn_global_load_lds(
      (const __attribute__((address_space(1))) void*)g,
      (__attribute__((address_space(3))) void*)l, 16, 0, 0);
}

#define BARRIER() asm volatile("s_barrier" ::: "memory")
#define VMCNT(n)  asm volatile("s_waitcnt vmcnt(" #n ")" ::: "memory")

// ---------------- workspace layout (bytes) ----------------
// normA fp32 [3][8][25][28] @ 0         (67200)
// Weff  fp32 [64][192]      @ 67584     (49152)
// beff  fp32 [192]          @ 116736    (768)
// cbe   fp32 [64]           @ 117504    (256)
// cwetb bf16 [64][9][64]    @ 117760    (73728)
// biasU fp32 [1600]         @ 191488    (6400)
// U     bf16 [1792][1600]   @ 197888    (5734400)  rows 1600+ = zero page
// xb    bf16 [32][256][1600]@ 5932288   (26214400)
// yb    bf16 [32][256][1600]@ 32146688  (26214400)   total ~58.4 MB

// ---------------- pre 1: BN folds + adjacency normalize ----------------
__global__ __launch_bounds__(256) void k_pre(
    fp A, fp W, fp b, fp g0, fp b0, fp cw, fp cb, fp g2, fp b2,
    float* normA, float* Weff, float* beff, float* cbe, unsigned short* cwetb)
{
  int gid = blockIdx.x * 256 + threadIdx.x;
  const float inv_s = rsqrtf(1.0f + 1e-5f);

  if (gid < 16800) {                      // normA[k][g][v][w pad28]
    int k  = gid / 5600;
    int r  = gid % 5600;
    int g  = r / 700;
    int r2 = r % 700;
    int v  = r2 / 28, w = r2 % 28;
    float val = 0.f;
    if (w < 25) {
      float s = 0.f;
      for (int vv = 0; vv < 25; vv++) s += A[((k*8+g)*25+vv)*25 + w];
      val = A[((k*8+g)*25+v)*25 + w] / (s + 0.001f);
    }
    normA[gid] = val;
    return;
  }
  gid -= 16800;
  if (gid < 12288) {                      // Weff[cin][192]
    int d = gid % 192;
    Weff[gid] = W[gid] * (g0[d] * inv_s);
    return;
  }
  gid -= 12288;
  if (gid < 192) {                        // beff
    beff[gid] = b[gid] * (g0[gid] * inv_s) + b0[gid];
    return;
  }
  gid -= 192;
  if (gid < 64) {                         // cbe
    cbe[gid] = cb[gid] * (g2[gid] * inv_s) + b2[gid];
    return;
  }
  gid -= 64;
  if (gid < 36864) {                      // cwetb[o][j][i] bf16
    int o = gid / 576, r = gid % 576;
    int j = r / 64, i = r % 64;
    cwetb[gid] = f2us(cw[(o*64+i)*9 + j] * (g2[o] * inv_s));
  }
}

// ---------------- pre 2: U rows via LDS-cached factors ----------------
__global__ __launch_bounds__(256) void k_pre2(
    const float* Weff, const float* beff, const float* normA, fp g1, fp b1,
    unsigned short* U, float* biasU)
{
  int m = blockIdx.x;                     // 1792 blocks
  int tid = threadIdx.x;
  if (m >= 1600) {                        // zero-pad rows (also k_tcn zero page)
    for (int k = tid; k < 1600; k += 256) U[(long long)m*1600 + k] = 0;
    return;
  }
  int c = m & 63, w = m >> 6, g = c & 7;
  __shared__ float nAL[75];               // [kk][vv] = normA[kk,g,vv,w]
  __shared__ float WeffL[192];            // [kk][cin]
  if (tid < 75) {
    int kk = tid / 25, vv = tid % 25;
    nAL[tid] = normA[((kk*8 + g)*25 + vv)*28 + w];
  }
  if (tid < 192) {
    int kk = tid >> 6, cin = tid & 63;
    WeffL[tid] = Weff[cin*192 + kk*64 + c];
  }
  __syncthreads();
  float s1 = g1[c] * rsqrtf(1.0f + 1e-5f);
  for (int k = tid; k < 1600; k += 256) {
    int cin = k / 25, vv = k - cin*25;
    float acc = WeffL[cin]       * nAL[vv]
              + WeffL[64 + cin]  * nAL[25 + vv]
              + WeffL[128 + cin] * nAL[50 + vv];
    acc *= s1;
    if (cin == c && vv == w) acc += 1.0f;  // residual folded into diagonal
    U[(long long)m*1600 + k] = f2us(acc);
  }
  if (tid == 0) {
    float acc = 0.f;
    for (int kk = 0; kk < 3; kk++) {
      float be = beff[kk*64 + c];
      for (int v = 0; v < 25; v++) acc += be * nAL[kk*25 + v];
    }
    biasU[m] = acc * s1 + b1[c];
  }
}

// ---------------- transpose x -> bf16 [n][t][cin*25+v] (LDS, coalesced) ----
__global__ __launch_bounds__(256) void k_xt(fp x, unsigned short* xb)
{
  int n = blockIdx.x >> 5, tb = blockIdx.x & 31, t0 = tb*8, tid = threadIdx.x;
  __shared__ unsigned short xs[64*8*26];
  for (int e = tid; e < 12800; e += 256) {
    int c = e / 200, r = e - c*200, tt = r / 25, v = r - tt*25;
    xs[(c*8 + tt)*26 + v] = f2us(x[((n*64 + c)*256 + t0 + tt)*25 + v]);
  }
  __syncthreads();
  for (int e = tid; e < 12800; e += 256) {
    int tt = e / 1600, q = e - tt*1600, c = q / 25, v = q - c*25;
    xb[(n*256 + t0 + tt)*1600 + q] = xs[(c*8 + tt)*26 + v];
  }
}

// ---------------- GCN GEMM: 256x256, 8 waves, 8-phase counted-vmcnt ------
// A = U [1792 x 1600], B = xb [8192 x 1600], both row-major over K (NT GEMM).
// 7 x 32 = 224 blocks; per-wave output 128m x 64n (acc 8x4 fragments).
// LDS: double-buffered A[256x64] + B[256x64] bf16 = 128 KiB.
// Pipeline: A-tile staged 2 tiles ahead (slot freed after ph3), B-tile 1
// tile ahead (halves in ph1/ph2). One vmcnt(4) per K-tile at ph4, issued
// after the next-next A stage: drains next tile's A+B, leaves the 4 newest
// A-loads in flight. Accumulation order (kt,ks) identical to prev version.
__global__ __launch_bounds__(512, 2) void k_gemm(
    const unsigned short* U, const unsigned short* xb, const float* biasU,
    unsigned short* yb)
{
  int bid = blockIdx.x;
  int lb  = (bid & 7) * 28 + (bid >> 3);     // bijective XCD swizzle (224%8==0)
  int bm = lb >> 5, bn = lb & 31;            // 7 x 32
  int tid = threadIdx.x, lane = tid & 63, wid = tid >> 6;
  int l15 = lane & 15, grp = lane >> 4;
  int wm = wid >> 2, wn = wid & 3;           // 2 x 4 wave grid

  __shared__ __align__(16) unsigned short AsB[2][16384];  // 2 x 32 KB
  __shared__ __align__(16) unsigned short BsB[2][16384];  // 2 x 32 KB

  // staging map: it-th load covers rows it*64 + (tid>>3), 16B group tid&7,
  // XOR-swizzled on the global source side (linear LDS deposit).
  int srow = tid >> 3, sli = tid & 7;
  int sgrp = sli ^ (srow & 7);
  const unsigned short* gA = U  + (long long)(bm*256 + srow)*1600 + sgrp*8;
  const unsigned short* gB = xb + (long long)(bn*256 + srow)*1600 + sgrp*8;

  auto stA = [&](int kt, int slot, int it){
    gload_lds16(gA + (long long)it*102400 + kt*64, &AsB[slot][(it*512 + tid)*8]);
  };
  auto stB = [&](int kt, int slot, int it){
    gload_lds16(gB + (long long)it*102400 + kt*64, &BsB[slot][(it*512 + tid)*8]);
  };

  int arow = wm*128 + l15;
  int brow = wn*64  + l15;
  int swz  = l15 & 7;
  auto rdA = [&](int slot, int i, int ks) -> short8 {
    return *(const short8*)(&AsB[slot][(arow + i*16)*64 + (((ks*4 + grp) ^ swz))*8]);
  };
  auto rdB = [&](int slot, int j, int ks) -> short8 {
    return *(const short8*)(&BsB[slot][(brow + j*16)*64 + (((ks*4 + grp) ^ swz))*8]);
  };

  floatx4 acc[8][4];
  #pragma unroll
  for (int i = 0; i < 8; i++)
    #pragma unroll
    for (int j = 0; j < 4; j++) acc[i][j] = (floatx4){0.f,0.f,0.f,0.f};

  // prologue: tile0 A+B, tile1 A; drain tile0, keep tile1.A in flight
  #pragma unroll
  for (int it = 0; it < 4; it++) stA(0, 0, it);
  #pragma unroll
  for (int it = 0; it < 4; it++) stB(0, 0, it);
  #pragma unroll
  for (int it = 0; it < 4; it++) stA(1, 1, it);
  VMCNT(4);
  BARRIER();

  for (int kt = 0; kt < 25; ++kt) {
    int cs = kt & 1, ns = cs ^ 1;

    // ---- phase 1: read a[0-3], b[0-1]; stage next B half0 ----
    short8 aR[2][4], bR[2][2];
    #pragma unroll
    for (int ks = 0; ks < 2; ks++)
      #pragma unroll
      for (int i = 0; i < 4; i++) aR[ks][i] = rdA(cs, i, ks);
    #pragma unroll
    for (int ks = 0; ks < 2; ks++)
      #pragma unroll
      for (int j = 0; j < 2; j++) bR[ks][j] = rdB(cs, j, ks);
    if (kt + 1 < 25) { stB(kt+1, ns, 0); stB(kt+1, ns, 1); }
    BARRIER();
    __builtin_amdgcn_sched_barrier(0);
    __builtin_amdgcn_s_setprio(1);
    #pragma unroll
    for (int ks = 0; ks < 2; ks++)
      #pragma unroll
      for (int i = 0; i < 4; i++)
        #pragma unroll
        for (int j = 0; j < 2; j++)
          acc[i][j] = __builtin_amdgcn_mfma_f32_16x16x32_bf16(aR[ks][i], bR[ks][j], acc[i][j], 0, 0, 0);
    __builtin_amdgcn_s_setprio(0);
    BARRIER();

    // ---- phase 2: read b[2-3]; stage next B half1 ----
    short8 bR2[2][2];
    #pragma unroll
    for (int ks = 0; ks < 2; ks++)
      #pragma unroll
      for (int j = 0; j < 2; j++) bR2[ks][j] = rdB(cs, 2 + j, ks);
    if (kt + 1 < 25) { stB(kt+1, ns, 2); stB(kt+1, ns, 3); }
    BARRIER();
    __builtin_amdgcn_sched_barrier(0);
    __builtin_amdgcn_s_setprio(1);
    #pragma unroll
    for (int ks = 0; ks < 2; ks++)
      #pragma unroll
      for (int i = 0; i < 4; i++)
        #pragma unroll
        for (int j = 0; j < 2; j++)
          acc[i][2+j] = __builtin_amdgcn_mfma_f32_16x16x32_bf16(aR[ks][i], bR2[ks][j], acc[i][2+j], 0, 0, 0);
    __builtin_amdgcn_s_setprio(0);
    BARRIER();

    // ---- phase 3: read a[4-7] (A slot fully read after this) ----
    short8 aR2[2][4];
    #pragma unroll
    for (int ks = 0; ks < 2; ks++)
      #pragma unroll
      for (int i = 0; i < 4; i++) aR2[ks][i] = rdA(cs, 4 + i, ks);
    BARRIER();
    __builtin_amdgcn_sched_barrier(0);
    __builtin_amdgcn_s_setprio(1);
    #pragma unroll
    for (int ks = 0; ks < 2; ks++)
      #pragma unroll
      for (int i = 0; i < 4; i++)
        #pragma unroll
        for (int j = 0; j < 2; j++)
          acc[4+i][2+j] = __builtin_amdgcn_mfma_f32_16x16x32_bf16(aR2[ks][i], bR2[ks][j], acc[4+i][2+j], 0, 0, 0);
    __builtin_amdgcn_s_setprio(0);
    BARRIER();

    // ---- phase 4: re-read b[0-1]; stage A(kt+2) into freed A slot;
    //      counted vmcnt leaves only the 4 new A-loads in flight ----
    short8 bR3[2][2];
    #pragma unroll
    for (int ks = 0; ks < 2; ks++)
      #pragma unroll
      for (int j = 0; j < 2; j++) bR3[ks][j] = rdB(cs, j, ks);
    if (kt + 2 < 25) {
      #pragma unroll
      for (int it = 0; it < 4; it++) stA(kt+2, cs, it);
      VMCNT(4);
    } else if (kt == 23) {
      VMCNT(0);                            // drain tile 24's A+B
    }
    BARRIER();
    __builtin_amdgcn_sched_barrier(0);
    __builtin_amdgcn_s_setprio(1);
    #pragma unroll
    for (int ks = 0; ks < 2; ks++)
      #pragma unroll
      for (int i = 0; i < 4; i++)
        #pragma unroll
        for (int j = 0; j < 2; j++)
          acc[4+i][j] = __builtin_amdgcn_mfma_f32_16x16x32_bf16(aR2[ks][i], bR3[ks][j], acc[4+i][j], 0, 0, 0);
    __builtin_amdgcn_s_setprio(0);
    BARRIER();
  }

  // epilogue: bias + relu + bf16 pack (C layout: m = grp*4+r, n = l15)
  #pragma unroll
  for (int i = 0; i < 8; i++) {
    int mb = bm*256 + wm*128 + i*16 + grp*4;
    if (mb >= 1600) continue;
    float4 bu = *(const float4*)(biasU + mb);
    #pragma unroll
    for (int j = 0; j < 4; j++) {
      int nrow = bn*256 + wn*64 + j*16 + l15;
      ushort4 pk;
      pk.x = f2us(fmaxf(acc[i][j][0] + bu.x, 0.f));
      pk.y = f2us(fmaxf(acc[i][j][1] + bu.y, 0.f));
      pk.z = f2us(fmaxf(acc[i][j][2] + bu.z, 0.f));
      pk.w = f2us(fmaxf(acc[i][j][3] + bu.w, 0.f));
      *(ushort4*)(yb + (long long)nrow*1600 + mb) = pk;
    }
  }
}

// ---------------- TCN as MFMA: 512 threads, DMA staging, tile split ----------
// 8 waves share one 57 KB window; wave pair (p, p+4) owns o-strip p*16 and
// splits the 13 col-tiles even/odd. Staging via global_load_lds (linear
// deposit = wave-uniform base + lane*16); OOB rows source from zpg (U pad
// rows, zeroed by k_pre2 each call) so every DMA issues with full exec.
__global__ __launch_bounds__(512) void k_tcn(
    const unsigned short* yb, const unsigned short* cwetb, const float* cbe,
    fp x, const unsigned short* zpg, float* out)
{
  int n = blockIdx.x >> 5, tb = blockIdx.x & 31, t0 = tb*8;
  int tid = threadIdx.x, lane = tid & 63, wid = tid >> 6;
  int l15 = lane & 15, grp = lane >> 4;
  __shared__ __align__(16) unsigned short ys[3584*8];  // 57344 B (425 rows + pad)

  #pragma unroll
  for (int it = 0; it < 7; it++) {
    int e = it*512 + tid;                 // e < 3584, always full exec
    int row = e >> 3, li = e & 7;
    int rt = row / 25, v = row - rt*25;
    int tg = t0 - 4 + rt;
    int sli = li ^ (row & 7);             // fetch swizzled i-group
    bool ok = (row < 425) && (tg >= 0) && (tg < 256);
    const unsigned short* src = ok
      ? yb + ((long long)(n*256 + tg)*1600 + v*64 + sli*8)
      : zpg + li*8;
    gload_lds16(src, ys + e*8);           // linear LDS deposit
  }

  // A-frags: conv weights in registers, o-strip p = wid&3, half h = wid>>2
  int p = wid & 3, h = wid >> 2;
  int o0 = p * 16;
  int o = o0 + l15;
  short8 af[9][2];
  #pragma unroll
  for (int j = 0; j < 9; j++) {
    af[j][0] = *(const short8*)(cwetb + ((o*9 + j)*64 + grp*8));
    af[j][1] = *(const short8*)(cwetb + ((o*9 + j)*64 + 32 + grp*8));
  }
  float4 cb4 = *(const float4*)(cbe + o0 + grp*4);
  __syncthreads();

  for (int tile = h; tile < 13; tile += 2) {
    int colb = tile*16 + l15;
    floatx4 acc = (floatx4){0.f,0.f,0.f,0.f};
    #pragma unroll
    for (int j = 0; j < 9; j++) {
      int row = colb + 25*j;
      int r7 = row & 7;
      const unsigned short* rb = ys + row*64;
      short8 b0 = *(const short8*)(rb + ((grp     ^ r7))*8);
      short8 b1 = *(const short8*)(rb + (((4+grp) ^ r7))*8);
      acc = __builtin_amdgcn_mfma_f32_16x16x32_bf16(af[j][0], b0, acc, 0, 0, 0);
      acc = __builtin_amdgcn_mfma_f32_16x16x32_bf16(af[j][1], b1, acc, 0, 0, 0);
    }
    if (colb < 200) {
      int tt = colb / 25, v = colb - tt*25, t = t0 + tt;
      #pragma unroll
      for (int r = 0; r < 4; r++) {
        int oo = o0 + grp*4 + r;
        float val = acc[r] + ((const float*)&cb4)[r]
                  + x[((n*64 + oo)*256 + t)*25 + v];
        out[((n*64 + oo)*256 + t)*25 + v] = fmaxf(val, 0.f);
      }
    }
  }
}

extern "C" void kernel_launch(void* const* d_in, const int* in_sizes, int n_in,
                              void* d_out, int out_size, void* d_ws, size_t ws_size,
                              hipStream_t stream)
{
  fp x  = (fp)d_in[0];
  fp A  = (fp)d_in[1];
  fp W  = (fp)d_in[2];
  fp b  = (fp)d_in[3];
  fp g0 = (fp)d_in[4];
  fp b0 = (fp)d_in[5];
  fp g1 = (fp)d_in[6];
  fp b1 = (fp)d_in[7];
  fp cw = (fp)d_in[8];
  fp cb = (fp)d_in[9];
  fp g2 = (fp)d_in[10];
  fp b2 = (fp)d_in[11];
  // d_in[12] = keep_prob == 1 -> DropBlocks identity.

  char* ws = (char*)d_ws;
  float*          normA = (float*)(ws + 0);
  float*          Weff  = (float*)(ws + 67584);
  float*          beff  = (float*)(ws + 116736);
  float*          cbe   = (float*)(ws + 117504);
  unsigned short* cwetb = (unsigned short*)(ws + 117760);
  float*          biasU = (float*)(ws + 191488);
  unsigned short* U     = (unsigned short*)(ws + 197888);
  unsigned short* xb    = (unsigned short*)(ws + 5932288);
  unsigned short* yb    = (unsigned short*)(ws + 32146688);
  const unsigned short* zpg = U + (long long)1600*1600;  // zeroed pad rows

  k_pre<<<259, 256, 0, stream>>>(A, W, b, g0, b0, cw, cb, g2, b2,
                                 normA, Weff, beff, cbe, cwetb);
  k_pre2<<<1792, 256, 0, stream>>>(Weff, beff, normA, g1, b1, U, biasU);
  k_xt<<<1024, 256, 0, stream>>>(x, xb);
  k_gemm<<<224, 512, 0, stream>>>(U, xb, biasU, yb);
  k_tcn<<<1024, 512, 0, stream>>>(yb, cwetb, cbe, x, zpg, (float*)d_out);
}

// Round 2
// 242.722 us; speedup vs baseline: 1.0146x; 1.0146x over previous
//
#include <hip/hip_runtime.h>
#include <hip/hip_bf16.h>
#include <stdint.h>

// Shapes: N=32, CIN=COUT=64, T=256, V=25, K3=3, G=8
// GCN folded to one GEMM: M=1600 (m=w*64+c), K=1600 (k=cin*25+v), N=8192 (n,t)
//   residual (+x) folded into U's diagonal: U[w*64+c][c*25+w] += 1
// k_gemm: 256x256 tile, 8 waves, 8-phase counted-vmcnt schedule (T2+T3+T4+T5)
//   Block mapping: bm=bid>>5, bn=bid&31 -> bid mod 8 = bn mod 8, so all 7
//   blocks sharing a B-panel land on one XCD (B re-reads are L2-local).
//   (R1 lesson: generic XCD swizzle broke this -> FETCH 35->95 MB, -30%.)
// k_tcn: MFMA im2col, 512-thread blocks (16 waves/CU), DMA staging
//   OOB window rows read from U's pad rows (zeroed by k_pre2 every call)

typedef const float* fp;
typedef __attribute__((ext_vector_type(8))) short short8;   // 8 bf16 (4 VGPRs)
typedef __attribute__((ext_vector_type(4))) float floatx4;  // MFMA acc

__device__ __forceinline__ float us2f(unsigned int u){
  union { unsigned int i; float f; } c; c.i = u << 16; return c.f;
}
__device__ __forceinline__ unsigned short f2us(float f){
  __hip_bfloat16 h = __float2bfloat16(f);
  return *reinterpret_cast<unsigned short*>(&h);
}
__device__ __forceinline__ void gload_lds16(const void* g, void* l){
  __builtin_amdgcn_global_load_lds(
      (const __attribute__((address_space(1))) void*)g,
      (__attribute__((address_space(3))) void*)l, 16, 0, 0);
}

#define BARRIER() asm volatile("s_barrier" ::: "memory")
#define VMCNT(n)  asm volatile("s_waitcnt vmcnt(" #n ")" ::: "memory")

// ---------------- workspace layout (bytes) ----------------
// normA fp32 [3][8][25][28] @ 0         (67200)
// Weff  fp32 [64][192]      @ 67584     (49152)
// beff  fp32 [192]          @ 116736    (768)
// cbe   fp32 [64]           @ 117504    (256)
// cwetb bf16 [64][9][64]    @ 117760    (73728)
// biasU fp32 [1600]         @ 191488    (6400)
// U     bf16 [1792][1600]   @ 197888    (5734400)  rows 1600+ = zero page
// xb    bf16 [32][256][1600]@ 5932288   (26214400)
// yb    bf16 [32][256][1600]@ 32146688  (26214400)   total ~58.4 MB

// ---------------- pre 1: BN folds + adjacency normalize ----------------
__global__ __launch_bounds__(256) void k_pre(
    fp A, fp W, fp b, fp g0, fp b0, fp cw, fp cb, fp g2, fp b2,
    float* normA, float* Weff, float* beff, float* cbe, unsigned short* cwetb)
{
  int gid = blockIdx.x * 256 + threadIdx.x;
  const float inv_s = rsqrtf(1.0f + 1e-5f);

  if (gid < 16800) {                      // normA[k][g][v][w pad28]
    int k  = gid / 5600;
    int r  = gid % 5600;
    int g  = r / 700;
    int r2 = r % 700;
    int v  = r2 / 28, w = r2 % 28;
    float val = 0.f;
    if (w < 25) {
      float s = 0.f;
      for (int vv = 0; vv < 25; vv++) s += A[((k*8+g)*25+vv)*25 + w];
      val = A[((k*8+g)*25+v)*25 + w] / (s + 0.001f);
    }
    normA[gid] = val;
    return;
  }
  gid -= 16800;
  if (gid < 12288) {                      // Weff[cin][192]
    int d = gid % 192;
    Weff[gid] = W[gid] * (g0[d] * inv_s);
    return;
  }
  gid -= 12288;
  if (gid < 192) {                        // beff
    beff[gid] = b[gid] * (g0[gid] * inv_s) + b0[gid];
    return;
  }
  gid -= 192;
  if (gid < 64) {                         // cbe
    cbe[gid] = cb[gid] * (g2[gid] * inv_s) + b2[gid];
    return;
  }
  gid -= 64;
  if (gid < 36864) {                      // cwetb[o][j][i] bf16
    int o = gid / 576, r = gid % 576;
    int j = r / 64, i = r % 64;
    cwetb[gid] = f2us(cw[(o*64+i)*9 + j] * (g2[o] * inv_s));
  }
}

// ---------------- pre 2: U rows via LDS-cached factors ----------------
__global__ __launch_bounds__(256) void k_pre2(
    const float* Weff, const float* beff, const float* normA, fp g1, fp b1,
    unsigned short* U, float* biasU)
{
  int m = blockIdx.x;                     // 1792 blocks
  int tid = threadIdx.x;
  if (m >= 1600) {                        // zero-pad rows (also k_tcn zero page)
    for (int k = tid; k < 1600; k += 256) U[(long long)m*1600 + k] = 0;
    return;
  }
  int c = m & 63, w = m >> 6, g = c & 7;
  __shared__ float nAL[75];               // [kk][vv] = normA[kk,g,vv,w]
  __shared__ float WeffL[192];            // [kk][cin]
  if (tid < 75) {
    int kk = tid / 25, vv = tid % 25;
    nAL[tid] = normA[((kk*8 + g)*25 + vv)*28 + w];
  }
  if (tid < 192) {
    int kk = tid >> 6, cin = tid & 63;
    WeffL[tid] = Weff[cin*192 + kk*64 + c];
  }
  __syncthreads();
  float s1 = g1[c] * rsqrtf(1.0f + 1e-5f);
  for (int k = tid; k < 1600; k += 256) {
    int cin = k / 25, vv = k - cin*25;
    float acc = WeffL[cin]       * nAL[vv]
              + WeffL[64 + cin]  * nAL[25 + vv]
              + WeffL[128 + cin] * nAL[50 + vv];
    acc *= s1;
    if (cin == c && vv == w) acc += 1.0f;  // residual folded into diagonal
    U[(long long)m*1600 + k] = f2us(acc);
  }
  if (tid == 0) {
    float acc = 0.f;
    for (int kk = 0; kk < 3; kk++) {
      float be = beff[kk*64 + c];
      for (int v = 0; v < 25; v++) acc += be * nAL[kk*25 + v];
    }
    biasU[m] = acc * s1 + b1[c];
  }
}

// ---------------- transpose x -> bf16 [n][t][cin*25+v] (LDS, coalesced) ----
__global__ __launch_bounds__(256) void k_xt(fp x, unsigned short* xb)
{
  int n = blockIdx.x >> 5, tb = blockIdx.x & 31, t0 = tb*8, tid = threadIdx.x;
  __shared__ unsigned short xs[64*8*26];
  for (int e = tid; e < 12800; e += 256) {
    int c = e / 200, r = e - c*200, tt = r / 25, v = r - tt*25;
    xs[(c*8 + tt)*26 + v] = f2us(x[((n*64 + c)*256 + t0 + tt)*25 + v]);
  }
  __syncthreads();
  for (int e = tid; e < 12800; e += 256) {
    int tt = e / 1600, q = e - tt*1600, c = q / 25, v = q - c*25;
    xb[(n*256 + t0 + tt)*1600 + q] = xs[(c*8 + tt)*26 + v];
  }
}

// ---------------- GCN GEMM: 256x256, 8 waves, 8-phase counted-vmcnt ------
// A = U [1792 x 1600], B = xb [8192 x 1600], both row-major over K (NT GEMM).
// 7 x 32 = 224 blocks; per-wave output 128m x 64n (acc 8x4 fragments).
// LDS: double-buffered A[256x64] + B[256x64] bf16 = 128 KiB.
// Pipeline: A-tile staged 2 tiles ahead (slot freed after ph3), B-tile 1
// tile ahead (halves in ph1/ph2). One vmcnt(4) per K-tile at ph4, issued
// after the next-next A stage: drains next tile's A+B, leaves the 4 newest
// A-loads in flight. Accumulation order (kt,ks) identical to R0 version.
__global__ __launch_bounds__(512, 2) void k_gemm(
    const unsigned short* U, const unsigned short* xb, const float* biasU,
    unsigned short* yb)
{
  int bid = blockIdx.x;
  // natural mapping: bid mod 8 = bn mod 8 -> B-panel reuse is XCD-local
  int bm = bid >> 5, bn = bid & 31;          // 7 x 32
  int tid = threadIdx.x, lane = tid & 63, wid = tid >> 6;
  int l15 = lane & 15, grp = lane >> 4;
  int wm = wid >> 2, wn = wid & 3;           // 2 x 4 wave grid

  __shared__ __align__(16) unsigned short AsB[2][16384];  // 2 x 32 KB
  __shared__ __align__(16) unsigned short BsB[2][16384];  // 2 x 32 KB

  // staging map: it-th load covers rows it*64 + (tid>>3), 16B group tid&7,
  // XOR-swizzled on the global source side (linear LDS deposit).
  int srow = tid >> 3, sli = tid & 7;
  int sgrp = sli ^ (srow & 7);
  const unsigned short* gA = U  + (long long)(bm*256 + srow)*1600 + sgrp*8;
  const unsigned short* gB = xb + (long long)(bn*256 + srow)*1600 + sgrp*8;

  auto stA = [&](int kt, int slot, int it){
    gload_lds16(gA + (long long)it*102400 + kt*64, &AsB[slot][(it*512 + tid)*8]);
  };
  auto stB = [&](int kt, int slot, int it){
    gload_lds16(gB + (long long)it*102400 + kt*64, &BsB[slot][(it*512 + tid)*8]);
  };

  int arow = wm*128 + l15;
  int brow = wn*64  + l15;
  int swz  = l15 & 7;
  auto rdA = [&](int slot, int i, int ks) -> short8 {
    return *(const short8*)(&AsB[slot][(arow + i*16)*64 + (((ks*4 + grp) ^ swz))*8]);
  };
  auto rdB = [&](int slot, int j, int ks) -> short8 {
    return *(const short8*)(&BsB[slot][(brow + j*16)*64 + (((ks*4 + grp) ^ swz))*8]);
  };

  floatx4 acc[8][4];
  #pragma unroll
  for (int i = 0; i < 8; i++)
    #pragma unroll
    for (int j = 0; j < 4; j++) acc[i][j] = (floatx4){0.f,0.f,0.f,0.f};

  // prologue: tile0 A+B, tile1 A; drain tile0, keep tile1.A in flight
  #pragma unroll
  for (int it = 0; it < 4; it++) stA(0, 0, it);
  #pragma unroll
  for (int it = 0; it < 4; it++) stB(0, 0, it);
  #pragma unroll
  for (int it = 0; it < 4; it++) stA(1, 1, it);
  VMCNT(4);
  BARRIER();

  for (int kt = 0; kt < 25; ++kt) {
    int cs = kt & 1, ns = cs ^ 1;

    // ---- phase 1: read a[0-3], b[0-1]; stage next B half0 ----
    short8 aR[2][4], bR[2][2];
    #pragma unroll
    for (int ks = 0; ks < 2; ks++)
      #pragma unroll
      for (int i = 0; i < 4; i++) aR[ks][i] = rdA(cs, i, ks);
    #pragma unroll
    for (int ks = 0; ks < 2; ks++)
      #pragma unroll
      for (int j = 0; j < 2; j++) bR[ks][j] = rdB(cs, j, ks);
    if (kt + 1 < 25) { stB(kt+1, ns, 0); stB(kt+1, ns, 1); }
    BARRIER();
    __builtin_amdgcn_sched_barrier(0);
    __builtin_amdgcn_s_setprio(1);
    #pragma unroll
    for (int ks = 0; ks < 2; ks++)
      #pragma unroll
      for (int i = 0; i < 4; i++)
        #pragma unroll
        for (int j = 0; j < 2; j++)
          acc[i][j] = __builtin_amdgcn_mfma_f32_16x16x32_bf16(aR[ks][i], bR[ks][j], acc[i][j], 0, 0, 0);
    __builtin_amdgcn_s_setprio(0);
    BARRIER();

    // ---- phase 2: read b[2-3]; stage next B half1 ----
    short8 bR2[2][2];
    #pragma unroll
    for (int ks = 0; ks < 2; ks++)
      #pragma unroll
      for (int j = 0; j < 2; j++) bR2[ks][j] = rdB(cs, 2 + j, ks);
    if (kt + 1 < 25) { stB(kt+1, ns, 2); stB(kt+1, ns, 3); }
    BARRIER();
    __builtin_amdgcn_sched_barrier(0);
    __builtin_amdgcn_s_setprio(1);
    #pragma unroll
    for (int ks = 0; ks < 2; ks++)
      #pragma unroll
      for (int i = 0; i < 4; i++)
        #pragma unroll
        for (int j = 0; j < 2; j++)
          acc[i][2+j] = __builtin_amdgcn_mfma_f32_16x16x32_bf16(aR[ks][i], bR2[ks][j], acc[i][2+j], 0, 0, 0);
    __builtin_amdgcn_s_setprio(0);
    BARRIER();

    // ---- phase 3: read a[4-7] (A slot fully read after this) ----
    short8 aR2[2][4];
    #pragma unroll
    for (int ks = 0; ks < 2; ks++)
      #pragma unroll
      for (int i = 0; i < 4; i++) aR2[ks][i] = rdA(cs, 4 + i, ks);
    BARRIER();
    __builtin_amdgcn_sched_barrier(0);
    __builtin_amdgcn_s_setprio(1);
    #pragma unroll
    for (int ks = 0; ks < 2; ks++)
      #pragma unroll
      for (int i = 0; i < 4; i++)
        #pragma unroll
        for (int j = 0; j < 2; j++)
          acc[4+i][2+j] = __builtin_amdgcn_mfma_f32_16x16x32_bf16(aR2[ks][i], bR2[ks][j], acc[4+i][2+j], 0, 0, 0);
    __builtin_amdgcn_s_setprio(0);
    BARRIER();

    // ---- phase 4: re-read b[0-1]; stage A(kt+2) into freed A slot;
    //      counted vmcnt leaves only the 4 new A-loads in flight ----
    short8 bR3[2][2];
    #pragma unroll
    for (int ks = 0; ks < 2; ks++)
      #pragma unroll
      for (int j = 0; j < 2; j++) bR3[ks][j] = rdB(cs, j, ks);
    if (kt + 2 < 25) {
      #pragma unroll
      for (int it = 0; it < 4; it++) stA(kt+2, cs, it);
      VMCNT(4);
    } else if (kt == 23) {
      VMCNT(0);                            // drain tile 24's A+B
    }
    BARRIER();
    __builtin_amdgcn_sched_barrier(0);
    __builtin_amdgcn_s_setprio(1);
    #pragma unroll
    for (int ks = 0; ks < 2; ks++)
      #pragma unroll
      for (int i = 0; i < 4; i++)
        #pragma unroll
        for (int j = 0; j < 2; j++)
          acc[4+i][j] = __builtin_amdgcn_mfma_f32_16x16x32_bf16(aR2[ks][i], bR3[ks][j], acc[4+i][j], 0, 0, 0);
    __builtin_amdgcn_s_setprio(0);
    BARRIER();
  }

  // epilogue: bias + relu + bf16 pack (C layout: m = grp*4+r, n = l15)
  #pragma unroll
  for (int i = 0; i < 8; i++) {
    int mb = bm*256 + wm*128 + i*16 + grp*4;
    if (mb >= 1600) continue;
    float4 bu = *(const float4*)(biasU + mb);
    #pragma unroll
    for (int j = 0; j < 4; j++) {
      int nrow = bn*256 + wn*64 + j*16 + l15;
      ushort4 pk;
      pk.x = f2us(fmaxf(acc[i][j][0] + bu.x, 0.f));
      pk.y = f2us(fmaxf(acc[i][j][1] + bu.y, 0.f));
      pk.z = f2us(fmaxf(acc[i][j][2] + bu.z, 0.f));
      pk.w = f2us(fmaxf(acc[i][j][3] + bu.w, 0.f));
      *(ushort4*)(yb + (long long)nrow*1600 + mb) = pk;
    }
  }
}

// ---------------- TCN as MFMA: 512 threads, DMA staging, tile split ----------
// 8 waves share one 57 KB window; wave pair (p, p+4) owns o-strip p*16 and
// splits the 13 col-tiles even/odd. Staging via global_load_lds (linear
// deposit = wave-uniform base + lane*16); OOB rows source from zpg (U pad
// rows, zeroed by k_pre2 each call) so every DMA issues with full exec.
__global__ __launch_bounds__(512) void k_tcn(
    const unsigned short* yb, const unsigned short* cwetb, const float* cbe,
    fp x, const unsigned short* zpg, float* out)
{
  int n = blockIdx.x >> 5, tb = blockIdx.x & 31, t0 = tb*8;
  int tid = threadIdx.x, lane = tid & 63, wid = tid >> 6;
  int l15 = lane & 15, grp = lane >> 4;
  __shared__ __align__(16) unsigned short ys[3584*8];  // 57344 B (425 rows + pad)

  #pragma unroll
  for (int it = 0; it < 7; it++) {
    int e = it*512 + tid;                 // e < 3584, always full exec
    int row = e >> 3, li = e & 7;
    int rt = row / 25, v = row - rt*25;
    int tg = t0 - 4 + rt;
    int sli = li ^ (row & 7);             // fetch swizzled i-group
    bool ok = (row < 425) && (tg >= 0) && (tg < 256);
    const unsigned short* src = ok
      ? yb + ((long long)(n*256 + tg)*1600 + v*64 + sli*8)
      : zpg + li*8;
    gload_lds16(src, ys + e*8);           // linear LDS deposit
  }

  // A-frags: conv weights in registers, o-strip p = wid&3, half h = wid>>2
  int p = wid & 3, h = wid >> 2;
  int o0 = p * 16;
  int o = o0 + l15;
  short8 af[9][2];
  #pragma unroll
  for (int j = 0; j < 9; j++) {
    af[j][0] = *(const short8*)(cwetb + ((o*9 + j)*64 + grp*8));
    af[j][1] = *(const short8*)(cwetb + ((o*9 + j)*64 + 32 + grp*8));
  }
  float4 cb4 = *(const float4*)(cbe + o0 + grp*4);
  __syncthreads();

  for (int tile = h; tile < 13; tile += 2) {
    int colb = tile*16 + l15;
    floatx4 acc = (floatx4){0.f,0.f,0.f,0.f};
    #pragma unroll
    for (int j = 0; j < 9; j++) {
      int row = colb + 25*j;
      int r7 = row & 7;
      const unsigned short* rb = ys + row*64;
      short8 b0 = *(const short8*)(rb + ((grp     ^ r7))*8);
      short8 b1 = *(const short8*)(rb + (((4+grp) ^ r7))*8);
      acc = __builtin_amdgcn_mfma_f32_16x16x32_bf16(af[j][0], b0, acc, 0, 0, 0);
      acc = __builtin_amdgcn_mfma_f32_16x16x32_bf16(af[j][1], b1, acc, 0, 0, 0);
    }
    if (colb < 200) {
      int tt = colb / 25, v = colb - tt*25, t = t0 + tt;
      #pragma unroll
      for (int r = 0; r < 4; r++) {
        int oo = o0 + grp*4 + r;
        float val = acc[r] + ((const float*)&cb4)[r]
                  + x[((n*64 + oo)*256 + t)*25 + v];
        out[((n*64 + oo)*256 + t)*25 + v] = fmaxf(val, 0.f);
      }
    }
  }
}

extern "C" void kernel_launch(void* const* d_in, const int* in_sizes, int n_in,
                              void* d_out, int out_size, void* d_ws, size_t ws_size,
                              hipStream_t stream)
{
  fp x  = (fp)d_in[0];
  fp A  = (fp)d_in[1];
  fp W  = (fp)d_in[2];
  fp b  = (fp)d_in[3];
  fp g0 = (fp)d_in[4];
  fp b0 = (fp)d_in[5];
  fp g1 = (fp)d_in[6];
  fp b1 = (fp)d_in[7];
  fp cw = (fp)d_in[8];
  fp cb = (fp)d_in[9];
  fp g2 = (fp)d_in[10];
  fp b2 = (fp)d_in[11];
  // d_in[12] = keep_prob == 1 -> DropBlocks identity.

  char* ws = (char*)d_ws;
  float*          normA = (float*)(ws + 0);
  float*          Weff  = (float*)(ws + 67584);
  float*          beff  = (float*)(ws + 116736);
  float*          cbe   = (float*)(ws + 117504);
  unsigned short* cwetb = (unsigned short*)(ws + 117760);
  float*          biasU = (float*)(ws + 191488);
  unsigned short* U     = (unsigned short*)(ws + 197888);
  unsigned short* xb    = (unsigned short*)(ws + 5932288);
  unsigned short* yb    = (unsigned short*)(ws + 32146688);
  const unsigned short* zpg = U + (long long)1600*1600;  // zeroed pad rows

  k_pre<<<259, 256, 0, stream>>>(A, W, b, g0, b0, cw, cb, g2, b2,
                                 normA, Weff, beff, cbe, cwetb);
  k_pre2<<<1792, 256, 0, stream>>>(Weff, beff, normA, g1, b1, U, biasU);
  k_xt<<<1024, 256, 0, stream>>>(x, xb);
  k_gemm<<<224, 512, 0, stream>>>(U, xb, biasU, yb);
  k_tcn<<<1024, 512, 0, stream>>>(yb, cwetb, cbe, x, zpg, (float*)d_out);
}

// Round 3
// 221.733 us; speedup vs baseline: 1.1106x; 1.0947x over previous
//
#include <hip/hip_runtime.h>
#include <hip/hip_bf16.h>
#include <stdint.h>

// Shapes: N=32, CIN=COUT=64, T=256, V=25, K3=3, G=8
// GCN folded to one GEMM: M=1600 (m=w*64+c), K=1600 (k=cin*25+v), N=8192 (n,t)
//   residual (+x) folded into U's diagonal: U[w*64+c][c*25+w] += 1
// k_prep: FUSED pre+pre2+xt (2961 blocks): U/biasU factors computed in-block
//   from A/W directly (no normA/Weff staging), x->xb transpose, cwetb/cbe tail.
// k_gemm: R0-proven 256m x 128n tiles, 2-barrier loop, 448 blocks, 2 blk/CU
//   (R1/R2 lesson: 8-phase 256^2 is 12us SLOWER here: 25 K-tiles + 224-block
//    grid = 1 blk/CU, no inter-block overlap; and generic XCD swizzle broke
//    B-panel L2 affinity, FETCH 35->95MB. Natural bid mapping keeps
//    bid mod 8 = bn mod 8 -> B-panel reuse XCD-local.)
// k_tcn: MFMA im2col, 512-thread blocks, DMA staging
//   OOB window rows read from U's pad rows (zeroed by k_prep every call)

typedef const float* fp;
typedef __attribute__((ext_vector_type(8))) short short8;   // 8 bf16 (4 VGPRs)
typedef __attribute__((ext_vector_type(4))) float floatx4;  // MFMA acc

__device__ __forceinline__ float us2f(unsigned int u){
  union { unsigned int i; float f; } c; c.i = u << 16; return c.f;
}
__device__ __forceinline__ unsigned short f2us(float f){
  __hip_bfloat16 h = __float2bfloat16(f);
  return *reinterpret_cast<unsigned short*>(&h);
}
__device__ __forceinline__ void gload_lds16(const void* g, void* l){
  __builtin_amdgcn_global_load_lds(
      (const __attribute__((address_space(1))) void*)g,
      (__attribute__((address_space(3))) void*)l, 16, 0, 0);
}

// ---------------- workspace layout (bytes) ----------------
// cbe   fp32 [64]           @ 117504    (256)
// cwetb bf16 [64][9][64]    @ 117760    (73728)
// biasU fp32 [1600]         @ 191488    (6400)
// U     bf16 [1792][1600]   @ 197888    (5734400)  rows 1600+ = zero page
// xb    bf16 [32][256][1600]@ 5932288   (26214400)
// yb    bf16 [32][256][1600]@ 32146688  (26214400)   total ~58.4 MB

// ---------------- fused prep ----------------
// blocks [0,1792): U row m + biasU[m]  (self-sufficient: factors from A,W,b)
// blocks [1792,2816): x -> xb bf16 transpose (block bxt = bid-1792)
// blocks [2816,2961): cwetb (36864) + cbe (64)
__global__ __launch_bounds__(256) void k_prep(
    fp x, fp A, fp W, fp b, fp g0, fp b0, fp g1, fp b1,
    fp cw, fp cb, fp g2, fp b2,
    unsigned short* U, float* biasU, unsigned short* xb,
    float* cbe, unsigned short* cwetb)
{
  int bid = blockIdx.x, tid = threadIdx.x;
  const float inv_s = rsqrtf(1.0f + 1e-5f);
  __shared__ __align__(16) char smemraw[26624];   // union: xt needs 26 KB

  if (bid < 1792) {                     // ---- U rows (was k_pre2) ----
    int m = bid;
    if (m >= 1600) {                    // zero-pad rows (k_tcn zero page)
      for (int k = tid; k < 1600; k += 256) U[(long long)m*1600 + k] = 0;
      return;
    }
    float* nAL   = (float*)smemraw;          // 75 floats
    float* WeffL = (float*)(smemraw + 512);  // 192 floats
    float* cs3   = (float*)(smemraw + 1408); // 3 floats
    int c = m & 63, w = m >> 6, g = c & 7;
    if (tid < 75) {                     // raw A column w for (kk,g)
      int kk = tid / 25, vv = tid % 25;
      nAL[tid] = A[((kk*8 + g)*25 + vv)*25 + w];
    }
    if (tid < 192) {                    // W col c scaled by folded BN0 gain
      int kk = tid >> 6, cin = tid & 63;
      WeffL[tid] = W[cin*192 + kk*64 + c] * (g0[kk*64 + c] * inv_s);
    }
    __syncthreads();
    if (tid < 3) {                      // column sums -> denominators
      float s = 0.f;
      for (int vv = 0; vv < 25; vv++) s += nAL[tid*25 + vv];
      cs3[tid] = s + 0.001f;
    }
    __syncthreads();
    if (tid < 75) nAL[tid] = nAL[tid] / cs3[tid/25];
    __syncthreads();
    float s1 = g1[c] * inv_s;
    for (int k = tid; k < 1600; k += 256) {
      int cin = k / 25, vv = k - cin*25;
      float acc = WeffL[cin]       * nAL[vv]
                + WeffL[64 + cin]  * nAL[25 + vv]
                + WeffL[128 + cin] * nAL[50 + vv];
      acc *= s1;
      if (cin == c && vv == w) acc += 1.0f;  // residual folded into diagonal
      U[(long long)m*1600 + k] = f2us(acc);
    }
    if (tid == 0) {
      float acc = 0.f;
      for (int kk = 0; kk < 3; kk++) {
        int d = kk*64 + c;
        float be = b[d] * (g0[d] * inv_s) + b0[d];
        for (int v = 0; v < 25; v++) acc += be * nAL[kk*25 + v];
      }
      biasU[m] = acc * s1 + b1[c];
    }
    return;
  }

  if (bid < 2816) {                     // ---- x -> xb transpose (was k_xt) ----
    int bxt = bid - 1792;
    int n = bxt >> 5, tb = bxt & 31, t0 = tb*8;
    unsigned short* xs = (unsigned short*)smemraw;  // [64*8][26]
    for (int e = tid; e < 12800; e += 256) {
      int c = e / 200, r = e - c*200, tt = r / 25, v = r - tt*25;
      xs[(c*8 + tt)*26 + v] = f2us(x[((n*64 + c)*256 + t0 + tt)*25 + v]);
    }
    __syncthreads();
    for (int e4 = tid; e4 < 3200; e4 += 256) {      // ushort4 stores
      int base = e4 * 4;
      int tt = base / 1600, q0 = base - tt*1600;
      int c = q0 / 25, v = q0 - c*25;
      ushort4 pk;
      pk.x = xs[(c*8 + tt)*26 + v]; if (++v == 25){v = 0; c++;}
      pk.y = xs[(c*8 + tt)*26 + v]; if (++v == 25){v = 0; c++;}
      pk.z = xs[(c*8 + tt)*26 + v]; if (++v == 25){v = 0; c++;}
      pk.w = xs[(c*8 + tt)*26 + v];
      *(ushort4*)(xb + (long long)(n*256 + t0 + tt)*1600 + q0) = pk;
    }
    return;
  }

  // ---- cwetb + cbe tail (was k_pre remainder) ----
  int gid = (bid - 2816)*256 + tid;
  if (gid < 36864) {                    // cwetb[o][j][i] bf16
    int o = gid / 576, r = gid % 576;
    int j = r / 64, i = r % 64;
    cwetb[gid] = f2us(cw[(o*64+i)*9 + j] * (g2[o] * inv_s));
    return;
  }
  gid -= 36864;
  if (gid < 64) {                       // cbe
    cbe[gid] = cb[gid] * (g2[gid] * inv_s) + b2[gid];
  }
}

// ---------------- GCN GEMM: 256m x 128n, private-A wave strips (R0) ------
__global__ __launch_bounds__(256, 2) void k_gemm(
    const unsigned short* U, const unsigned short* xb, const float* biasU,
    unsigned short* yb)
{
  int bm = blockIdx.x >> 6, bn = blockIdx.x & 63;   // 7 x 64
  int n = bn >> 1, t0 = (bn & 1) * 128;
  int tid = threadIdx.x, lane = tid & 63, wid = tid >> 6;
  int l15 = lane & 15, grp = lane >> 4;

  __shared__ __align__(16) unsigned short As[256*64];  // 32 KB
  __shared__ __align__(16) unsigned short Bs[128*64];  // 16 KB

  const unsigned short* gA[8];
  const unsigned short* gB[4];
  unsigned short* lA[8];
  unsigned short* lB[4];
  #pragma unroll
  for (int it = 0; it < 8; it++) {
    int e = it*256 + tid;
    int row = e >> 3, li = e & 7;
    int kcol = (li ^ (row & 7)) * 8;       // XOR swizzle on global source side
    gA[it] = U + (long long)(bm*256 + row)*1600 + kcol;
    lA[it] = As + e*8;
  }
  #pragma unroll
  for (int it = 0; it < 4; it++) {
    int e = it*256 + tid;
    int row = e >> 3, li = e & 7;
    int kcol = (li ^ (row & 7)) * 8;
    gB[it] = xb + (long long)(n*256 + t0 + row)*1600 + kcol;
    lB[it] = Bs + e*8;
  }

  floatx4 acc[4][8];
  #pragma unroll
  for (int i = 0; i < 4; i++)
    #pragma unroll
    for (int j = 0; j < 8; j++) acc[i][j] = (floatx4){0.f,0.f,0.f,0.f};

  for (int kc = 0; kc < 25; kc++) {
    #pragma unroll
    for (int it = 0; it < 8; it++) gload_lds16(gA[it] + kc*64, lA[it]);
    #pragma unroll
    for (int it = 0; it < 4; it++) gload_lds16(gB[it] + kc*64, lB[it]);
    __syncthreads();
    #pragma unroll
    for (int ks = 0; ks < 2; ks++) {
      int colk = ((ks*4 + grp) ^ (l15 & 7)) * 8;   // un-swizzle at read
      short8 af[4], bf[8];
      #pragma unroll
      for (int i = 0; i < 4; i++)
        af[i] = *(const short8*)(As + (wid*64 + i*16 + l15)*64 + colk);
      #pragma unroll
      for (int j = 0; j < 8; j++)
        bf[j] = *(const short8*)(Bs + (j*16 + l15)*64 + colk);
      #pragma unroll
      for (int i = 0; i < 4; i++)
        #pragma unroll
        for (int j = 0; j < 8; j++)
          acc[i][j] = __builtin_amdgcn_mfma_f32_16x16x32_bf16(af[i], bf[j], acc[i][j], 0, 0, 0);
    }
    __syncthreads();
  }

  #pragma unroll
  for (int i = 0; i < 4; i++) {
    int mbase = bm*256 + wid*64 + i*16 + grp*4;
    if (mbase >= 1600) continue;
    float4 bu = *(const float4*)(biasU + mbase);
    #pragma unroll
    for (int j = 0; j < 8; j++) {
      int col = j*16 + l15;
      int t = t0 + col;
      ushort4 pk;
      pk.x = f2us(fmaxf(acc[i][j][0] + bu.x, 0.f));
      pk.y = f2us(fmaxf(acc[i][j][1] + bu.y, 0.f));
      pk.z = f2us(fmaxf(acc[i][j][2] + bu.z, 0.f));
      pk.w = f2us(fmaxf(acc[i][j][3] + bu.w, 0.f));
      *(ushort4*)(yb + (long long)(n*256 + t)*1600 + mbase) = pk;
    }
  }
}

// ---------------- TCN as MFMA: 512 threads, DMA staging, tile split ----------
// 8 waves share one 57 KB window; wave pair (p, p+4) owns o-strip p*16 and
// splits the 13 col-tiles even/odd. Staging via global_load_lds (linear
// deposit = wave-uniform base + lane*16); OOB rows source from zpg (U pad
// rows, zeroed by k_prep each call) so every DMA issues with full exec.
__global__ __launch_bounds__(512) void k_tcn(
    const unsigned short* yb, const unsigned short* cwetb, const float* cbe,
    fp x, const unsigned short* zpg, float* out)
{
  int n = blockIdx.x >> 5, tb = blockIdx.x & 31, t0 = tb*8;
  int tid = threadIdx.x, lane = tid & 63, wid = tid >> 6;
  int l15 = lane & 15, grp = lane >> 4;
  __shared__ __align__(16) unsigned short ys[3584*8];  // 57344 B (425 rows + pad)

  #pragma unroll
  for (int it = 0; it < 7; it++) {
    int e = it*512 + tid;                 // e < 3584, always full exec
    int row = e >> 3, li = e & 7;
    int rt = row / 25, v = row - rt*25;
    int tg = t0 - 4 + rt;
    int sli = li ^ (row & 7);             // fetch swizzled i-group
    bool ok = (row < 425) && (tg >= 0) && (tg < 256);
    const unsigned short* src = ok
      ? yb + ((long long)(n*256 + tg)*1600 + v*64 + sli*8)
      : zpg + li*8;
    gload_lds16(src, ys + e*8);           // linear LDS deposit
  }

  // A-frags: conv weights in registers, o-strip p = wid&3, half h = wid>>2
  int p = wid & 3, h = wid >> 2;
  int o0 = p * 16;
  int o = o0 + l15;
  short8 af[9][2];
  #pragma unroll
  for (int j = 0; j < 9; j++) {
    af[j][0] = *(const short8*)(cwetb + ((o*9 + j)*64 + grp*8));
    af[j][1] = *(const short8*)(cwetb + ((o*9 + j)*64 + 32 + grp*8));
  }
  float4 cb4 = *(const float4*)(cbe + o0 + grp*4);
  __syncthreads();

  for (int tile = h; tile < 13; tile += 2) {
    int colb = tile*16 + l15;
    floatx4 acc = (floatx4){0.f,0.f,0.f,0.f};
    #pragma unroll
    for (int j = 0; j < 9; j++) {
      int row = colb + 25*j;
      int r7 = row & 7;
      const unsigned short* rb = ys + row*64;
      short8 b0 = *(const short8*)(rb + ((grp     ^ r7))*8);
      short8 b1 = *(const short8*)(rb + (((4+grp) ^ r7))*8);
      acc = __builtin_amdgcn_mfma_f32_16x16x32_bf16(af[j][0], b0, acc, 0, 0, 0);
      acc = __builtin_amdgcn_mfma_f32_16x16x32_bf16(af[j][1], b1, acc, 0, 0, 0);
    }
    if (colb < 200) {
      int tt = colb / 25, v = colb - tt*25, t = t0 + tt;
      #pragma unroll
      for (int r = 0; r < 4; r++) {
        int oo = o0 + grp*4 + r;
        float val = acc[r] + ((const float*)&cb4)[r]
                  + x[((n*64 + oo)*256 + t)*25 + v];
        out[((n*64 + oo)*256 + t)*25 + v] = fmaxf(val, 0.f);
      }
    }
  }
}

extern "C" void kernel_launch(void* const* d_in, const int* in_sizes, int n_in,
                              void* d_out, int out_size, void* d_ws, size_t ws_size,
                              hipStream_t stream)
{
  fp x  = (fp)d_in[0];
  fp A  = (fp)d_in[1];
  fp W  = (fp)d_in[2];
  fp b  = (fp)d_in[3];
  fp g0 = (fp)d_in[4];
  fp b0 = (fp)d_in[5];
  fp g1 = (fp)d_in[6];
  fp b1 = (fp)d_in[7];
  fp cw = (fp)d_in[8];
  fp cb = (fp)d_in[9];
  fp g2 = (fp)d_in[10];
  fp b2 = (fp)d_in[11];
  // d_in[12] = keep_prob == 1 -> DropBlocks identity.

  char* ws = (char*)d_ws;
  float*          cbe   = (float*)(ws + 117504);
  unsigned short* cwetb = (unsigned short*)(ws + 117760);
  float*          biasU = (float*)(ws + 191488);
  unsigned short* U     = (unsigned short*)(ws + 197888);
  unsigned short* xb    = (unsigned short*)(ws + 5932288);
  unsigned short* yb    = (unsigned short*)(ws + 32146688);
  const unsigned short* zpg = U + (long long)1600*1600;  // zeroed pad rows

  k_prep<<<2961, 256, 0, stream>>>(x, A, W, b, g0, b0, g1, b1, cw, cb, g2, b2,
                                   U, biasU, xb, cbe, cwetb);
  k_gemm<<<448, 256, 0, stream>>>(U, xb, biasU, yb);
  k_tcn<<<1024, 512, 0, stream>>>(yb, cwetb, cbe, x, zpg, (float*)d_out);
}